// Round 8
// baseline (624.298 us; speedup 1.0000x reference)
//
#include <hip/hip_runtime.h>
#include <hip/hip_bf16.h>
#include <math.h>

typedef __bf16 bf16_t;
typedef __attribute__((ext_vector_type(2))) __bf16 bf16x2;
typedef __attribute__((ext_vector_type(4))) __bf16 bf16x4;
typedef __attribute__((ext_vector_type(8))) __bf16 bf16x8;
typedef __attribute__((ext_vector_type(4))) float f32x4;

#define BATCH  2
#define SEQ    2048
#define DMODEL 1024
#define NHEADS 16
#define DK     64

typedef const __attribute__((address_space(1))) void* gas_t;
typedef __attribute__((address_space(3))) void* las_t;

// ---------------------------------------------------------------------------
// fp32 -> bf16 convert for x, qkv_proj, o_proj (8 elems/thread).
// ---------------------------------------------------------------------------
#define X_N (BATCH * SEQ * DMODEL)        // 4,194,304
#define W_N (3 * DMODEL * DMODEL)         // 3,145,728
#define O_N (DMODEL * DMODEL)             // 1,048,576

__global__ __launch_bounds__(256) void convert_kernel(
    const float* __restrict__ x, const float* __restrict__ w, const float* __restrict__ o,
    bf16_t* __restrict__ xb, bf16_t* __restrict__ wb, bf16_t* __restrict__ ob)
{
    const int gid = blockIdx.x * 256 + threadIdx.x;   // 1,048,576 threads
    const float* src; bf16_t* dst; int base = gid * 8;
    if (base < X_N)                { src = x; dst = xb; }
    else if (base < X_N + W_N)     { src = w; dst = wb; base -= X_N; }
    else                           { src = o; dst = ob; base -= X_N + W_N; }
    const f32x4 lo = *(const f32x4*)(src + base);
    const f32x4 hi = *(const f32x4*)(src + base + 4);
    bf16x8 r;
    r[0] = (bf16_t)lo[0]; r[1] = (bf16_t)lo[1]; r[2] = (bf16_t)lo[2]; r[3] = (bf16_t)lo[3];
    r[4] = (bf16_t)hi[0]; r[5] = (bf16_t)hi[1]; r[6] = (bf16_t)hi[2]; r[7] = (bf16_t)hi[3];
    *(bf16x8*)(dst + base) = r;
}

// ---------------------------------------------------------------------------
// m97-style 128x128 GEMM body (unchanged).
// ---------------------------------------------------------------------------
__device__ __forceinline__ void gemm128_body(
    const bf16_t* __restrict__ A, const bf16_t* __restrict__ B,
    int rowBase, int colBase, bf16_t* ldsA, bf16_t* ldsB, f32x4 acc[4][4])
{
    const int tid  = threadIdx.x;
    const int lane = tid & 63;
    const int l15  = lane & 15, quad = lane >> 4;
    const int qr   = ((tid >> 6) >> 1) * 64;
    const int qc   = ((tid >> 6) & 1) * 64;

    const int c0 = tid, c1 = tid + 256;
    const int r0 = c0 >> 2, kc0 = (c0 & 3) * 8;
    const int r1 = c1 >> 2, kc1 = (c1 & 3) * 8;
    const bf16_t* ga0 = A + (size_t)(rowBase + r0) * DMODEL + kc0;
    const bf16_t* ga1 = A + (size_t)(rowBase + r1) * DMODEL + kc1;
    const bf16_t* gb0 = B + (size_t)(colBase + r0) * DMODEL + kc0;
    const bf16_t* gb1 = B + (size_t)(colBase + r1) * DMODEL + kc1;

    for (int k0 = 0; k0 < DMODEL; k0 += 32) {
        __syncthreads();
        __builtin_amdgcn_global_load_lds((gas_t)(ga0 + k0), (las_t)(ldsA + c0 * 8), 16, 0, 0);
        __builtin_amdgcn_global_load_lds((gas_t)(ga1 + k0), (las_t)(ldsA + c1 * 8), 16, 0, 0);
        __builtin_amdgcn_global_load_lds((gas_t)(gb0 + k0), (las_t)(ldsB + c0 * 8), 16, 0, 0);
        __builtin_amdgcn_global_load_lds((gas_t)(gb1 + k0), (las_t)(ldsB + c1 * 8), 16, 0, 0);
        __syncthreads();

        bf16x8 af[4], bfr[4];
#pragma unroll
        for (int i = 0; i < 4; ++i)
            af[i] = *(const bf16x8*)&ldsA[(qr + i * 16 + l15) * 32 + quad * 8];
#pragma unroll
        for (int j = 0; j < 4; ++j)
            bfr[j] = *(const bf16x8*)&ldsB[(qc + j * 16 + l15) * 32 + quad * 8];
#pragma unroll
        for (int i = 0; i < 4; ++i)
#pragma unroll
            for (int j = 0; j < 4; ++j)
                acc[i][j] = __builtin_amdgcn_mfma_f32_16x16x32_bf16(af[i], bfr[j], acc[i][j], 0, 0, 0);
    }
}

// ---------------------------------------------------------------------------
// QKV GEMM with FUSED RoPE. Epilogue: rope(q,k) in fp32 via lane-pair shfl,
// then scatter to head-major bf16 Q/K/V. RoPE pair (2i, 2i+1) = adjacent l15
// lanes (same quad, same row): even lane x1' = x1*c - x2*sn, odd x2' =
// x1*sn + x2*c, with c/sn per-lane from ifreq = d>>1 (shared by the pair).
// ---------------------------------------------------------------------------
__global__ __launch_bounds__(256) void qkv_gemm_kernel(
    const bf16_t* __restrict__ x, const bf16_t* __restrict__ w,
    const int* __restrict__ pos,
    bf16_t* __restrict__ qo, bf16_t* __restrict__ ko, bf16_t* __restrict__ vo)
{
    __shared__ bf16_t ldsA[128 * 32];
    __shared__ bf16_t ldsB[128 * 32];
    const int rowBase = blockIdx.y * 128;
    const int colBase = blockIdx.x * 128;
    f32x4 acc[4][4] = {};
    gemm128_body(x, w, rowBase, colBase, ldsA, ldsB, acc);

    const int lane = threadIdx.x & 63;
    const int l15 = lane & 15, quad = lane >> 4;
    const int qr = ((threadIdx.x >> 6) >> 1) * 64;
    const int qc = ((threadIdx.x >> 6) & 1) * 64;
#pragma unroll
    for (int j = 0; j < 4; ++j) {
        const int col  = colBase + qc + j * 16 + l15;
        const int part = col >> 10;             // wave-uniform (l15 < 16)
        const int h    = (col & 1023) >> 6;
        const int d    = col & 63;
        bf16_t* op = (part == 0) ? qo : (part == 1) ? ko : vo;
        if (part < 2) {
            // theta^(-2*(d>>1)/64) = 2^(-(d>>1) * 2*log2(1e4)/64)
            const float invf  = exp2f(-(float)(d >> 1) * 0.4152410118609203f);
            const float psign = (d & 1) ? 1.f : -1.f;
#pragma unroll
            for (int i = 0; i < 4; ++i) {
#pragma unroll
                for (int r = 0; r < 4; ++r) {
                    const int m = rowBase + qr + i * 16 + quad * 4 + r;
                    const int b = m >> 11;
                    const int s = m & (SEQ - 1);
                    const float ang = (float)pos[s] * invf;
                    float sn_, c_;
                    sincosf(ang, &sn_, &c_);
                    const float v = acc[i][j][r];
                    const float p = __shfl_xor(v, 1);
                    const float res = fmaf(p, psign * sn_, v * c_);
                    op[((size_t)(b * NHEADS + h) * SEQ + s) * DK + d] = (bf16_t)res;
                }
            }
        } else {
#pragma unroll
            for (int i = 0; i < 4; ++i) {
#pragma unroll
                for (int r = 0; r < 4; ++r) {
                    const int m = rowBase + qr + i * 16 + quad * 4 + r;
                    const int b = m >> 11;
                    const int s = m & (SEQ - 1);
                    op[((size_t)(b * NHEADS + h) * SEQ + s) * DK + d] = (bf16_t)acc[i][j][r];
                }
            }
        }
    }
}

// Output GEMM: M=4096, N=1024, fp32 direct-store epilogue.
__global__ __launch_bounds__(256) void out_gemm_kernel(
    const bf16_t* __restrict__ a, const bf16_t* __restrict__ w, float* __restrict__ out)
{
    __shared__ bf16_t ldsA[128 * 32];
    __shared__ bf16_t ldsB[128 * 32];
    const int rowBase = blockIdx.y * 128;
    const int colBase = blockIdx.x * 128;
    f32x4 acc[4][4] = {};
    gemm128_body(a, w, rowBase, colBase, ldsA, ldsB, acc);

    const int lane = threadIdx.x & 63;
    const int l15 = lane & 15, quad = lane >> 4;
    const int qr = ((threadIdx.x >> 6) >> 1) * 64;
    const int qc = ((threadIdx.x >> 6) & 1) * 64;
#pragma unroll
    for (int i = 0; i < 4; ++i) {
#pragma unroll
        for (int r = 0; r < 4; ++r) {
            const int m = rowBase + qr + i * 16 + quad * 4 + r;
#pragma unroll
            for (int j = 0; j < 4; ++j)
                out[(size_t)m * DMODEL + colBase + qc + j * 16 + l15] = acc[i][j][r];
        }
    }
}

// ---------------------------------------------------------------------------
// Split-K flash attention (v5): static-shift softmax p = exp(s/8 - 8) makes
// key-chunks independent -> partial (sum p*V, sum p) accumulated with f32
// atomics. Block = (bh, qblk, chunk of <=8 key-tiles); grid 80x32 uniform.
// Inner loop = v7 structure: K fragments prefetched in regs, Vt double-
// buffered (1 barrier/tile), packed-P b64 in permuted key order.
// ---------------------------------------------------------------------------
__global__ __launch_bounds__(256) void attn_kernel(
    const bf16_t* __restrict__ Q, const bf16_t* __restrict__ K,
    const bf16_t* __restrict__ V,
    float* __restrict__ OAcc, float* __restrict__ LAcc)
{
    __shared__ bf16_t Vt[2][64 * 72];    // [buf][d][pos], stride 72, swizzled
    __shared__ bf16_t Pb[4][16 * 72];    // per-wave P, [q][pos], stride 72

    const int bh = blockIdx.y;                   // 0..31
    // x -> (qblk, chunk); reversed so 8-tile chunks dispatch first
    const int x = 79 - blockIdx.x;
    int qblk, chunk;
    if (x < 8)       { qblk = x;                  chunk = 0; }
    else if (x < 24) { qblk = 8  + ((x - 8) >> 1);  chunk = (x - 8) & 1; }
    else if (x < 48) { qblk = 16 + (x - 24) / 3;    chunk = (x - 24) % 3; }
    else             { qblk = 24 + ((x - 48) >> 2); chunk = (x - 48) & 3; }
    const int kb0 = chunk * 8;
    const int kbe = min(qblk + 1, kb0 + 8);      // exclusive tile end

    const int tid  = threadIdx.x;
    const int wave = tid >> 6, lane = tid & 63;
    const int l15  = lane & 15, quad = lane >> 4;
    const int q0   = qblk * 64 + wave * 16;
    const size_t hb = (size_t)bh * SEQ * DK;

    // Q fragments, pre-scaled by 1/8 (exact in bf16)
    const bf16_t* qrow = Q + hb + (size_t)(q0 + l15) * DK + quad * 8;
    bf16x8 aq0 = *(const bf16x8*)qrow;
    bf16x8 aq1 = *(const bf16x8*)(qrow + 32);
#pragma unroll
    for (int i = 0; i < 8; ++i) {
        aq0[i] = (bf16_t)((float)aq0[i] * 0.125f);
        aq1[i] = (bf16_t)((float)aq1[i] * 0.125f);
    }

    f32x4 oacc[4] = {};
    float lsum[4] = {0.f, 0.f, 0.f, 0.f};

    // V staging task: thread (cgi, rr) stages d-group cgi of key rows k1, k1+16
    const int cgi = tid & 7;
    const int rr  = tid >> 3;
    const int k1  = (rr & 15) + ((rr >> 4) << 5);
    const int vpos = ((k1 & 15) << 2) + (k1 >> 4);        // even
    const int vsw  = vpos ^ (cgi << 3);                   // swizzled, still even
    const bf16_t* vst_g = V + hb + k1 * 64 + cgi * 8;
    const bf16_t* kfr_g = K + hb + l15 * 64 + quad * 8;   // B[k=d][n=key]

    // ---- prologue: tile kb0 -> K regs + Vt[kb0&1] ----
    bf16x8 kf0[4], kf1[4];
    {
        const bf16_t* kg = kfr_g + (size_t)kb0 * 4096;
#pragma unroll
        for (int c = 0; c < 4; ++c) {
            kf0[c] = *(const bf16x8*)(kg + c * 1024);
            kf1[c] = *(const bf16x8*)(kg + c * 1024 + 32);
        }
        const bf16x8 v1 = *(const bf16x8*)(vst_g + (size_t)kb0 * 4096);
        const bf16x8 v2 = *(const bf16x8*)(vst_g + (size_t)kb0 * 4096 + 1024);
#pragma unroll
        for (int j = 0; j < 8; ++j)
            *(bf16x2*)&Vt[kb0 & 1][(cgi * 8 + j) * 72 + vsw] = (bf16x2){v1[j], v2[j]};
    }

    for (int kb = kb0; kb < kbe; ++kb) {
        const int buf = kb & 1;
        __syncthreads();   // Vt[buf] staged; prior reads of Vt[buf^1] done

        // ---- prefetch tile kb+1 into regs ----
        const bool pf = (kb + 1 < kbe);
        bf16x8 kn0[4], kn1[4], v1n, v2n;
        if (pf) {
            const bf16_t* kg = kfr_g + (size_t)(kb + 1) * 4096;
#pragma unroll
            for (int c = 0; c < 4; ++c) {
                kn0[c] = *(const bf16x8*)(kg + c * 1024);
                kn1[c] = *(const bf16x8*)(kg + c * 1024 + 32);
            }
            v1n = *(const bf16x8*)(vst_g + (size_t)(kb + 1) * 4096);
            v2n = *(const bf16x8*)(vst_g + (size_t)(kb + 1) * 4096 + 1024);
        }

        // ---- scores: S = (Q/8) . K^T, K operands in registers ----
        const bool diag = (kb == qblk);
        f32x4 sc[4];
#pragma unroll
        for (int c = 0; c < 4; ++c) {
            f32x4 z = {};
            z = __builtin_amdgcn_mfma_f32_16x16x32_bf16(aq0, kf0[c], z, 0, 0, 0);
            z = __builtin_amdgcn_mfma_f32_16x16x32_bf16(aq1, kf1[c], z, 0, 0, 0);
            sc[c] = z;
        }

        // ---- p = exp(s - 8); packed b64 P store in permuted key order ----
#pragma unroll
        for (int r = 0; r < 4; ++r) {
            bf16x4 pr;
#pragma unroll
            for (int c = 0; c < 4; ++c) {
                float s = sc[c][r];
                if (diag) {
                    const int key = kb * 64 + c * 16 + l15;
                    const int qa  = q0 + quad * 4 + r;
                    s = (key <= qa) ? s : -INFINITY;
                }
                const float p = __expf(s - 8.0f);
                lsum[r] += p;
                pr[c] = (bf16_t)p;
            }
            *(bf16x4*)&Pb[wave][(quad * 4 + r) * 72 + l15 * 4] = pr;
        }
        asm volatile("s_waitcnt lgkmcnt(0)" ::: "memory");  // wave-private LDS RAW
        const bf16x8 ap0 = *(const bf16x8*)&Pb[wave][l15 * 72 + quad * 8];
        const bf16x8 ap1 = *(const bf16x8*)&Pb[wave][l15 * 72 + 32 + quad * 8];

        // ---- O += P . V ----
#pragma unroll
        for (int t = 0; t < 4; ++t) {
            const int dd = t * 2 + (l15 >> 3);
            const bf16_t* vrow = &Vt[buf][(t * 16 + l15) * 72];
            const bf16x8 bv0 = *(const bf16x8*)(vrow + ((quad ^ dd) << 3));
            const bf16x8 bv1 = *(const bf16x8*)(vrow + (((4 + quad) ^ dd) << 3));
            oacc[t] = __builtin_amdgcn_mfma_f32_16x16x32_bf16(ap0, bv0, oacc[t], 0, 0, 0);
            oacc[t] = __builtin_amdgcn_mfma_f32_16x16x32_bf16(ap1, bv1, oacc[t], 0, 0, 0);
        }

        // ---- commit prefetch ----
        if (pf) {
#pragma unroll
            for (int c = 0; c < 4; ++c) { kf0[c] = kn0[c]; kf1[c] = kn1[c]; }
#pragma unroll
            for (int j = 0; j < 8; ++j)
                *(bf16x2*)&Vt[buf ^ 1][(cgi * 8 + j) * 72 + vsw] = (bf16x2){v1n[j], v2n[j]};
        }
    }

    // ---- partial epilogue: atomically accumulate (O, l) in fp32 ----
    const int b = bh >> 4, h = bh & 15;
#pragma unroll
    for (int r = 0; r < 4; ++r) {
        float s = lsum[r];
        s += __shfl_xor(s, 1);
        s += __shfl_xor(s, 2);
        s += __shfl_xor(s, 4);
        s += __shfl_xor(s, 8);
        if (l15 == 0)
            unsafeAtomicAdd(&LAcc[(size_t)bh * SEQ + (q0 + quad * 4 + r)], s);
    }
#pragma unroll
    for (int t = 0; t < 4; ++t) {
#pragma unroll
        for (int r = 0; r < 4; ++r) {
            const int qa = q0 + quad * 4 + r;
            unsafeAtomicAdd(&OAcc[(size_t)(b * SEQ + qa) * DMODEL + h * 64 + t * 16 + l15],
                            oacc[t][r]);
        }
    }
}

// ---------------------------------------------------------------------------
// Normalize: AO_bf16 = OAcc / LAcc  (4 elems/thread).
// ---------------------------------------------------------------------------
__global__ __launch_bounds__(256) void norm_kernel(
    const float* __restrict__ OAcc, const float* __restrict__ LAcc,
    bf16_t* __restrict__ AO)
{
    const int gid = blockIdx.x * 256 + threadIdx.x;   // 1,048,576 threads
    const int m  = gid >> 8;
    const int c4 = (gid & 255) * 4;
    const int h  = c4 >> 6;
    const int b  = m >> 11;
    const int s  = m & (SEQ - 1);
    const float inv = 1.0f / LAcc[(size_t)(b * NHEADS + h) * SEQ + s];
    const f32x4 o = *(const f32x4*)&OAcc[(size_t)m * DMODEL + c4];
    bf16x4 r;
    r[0] = (bf16_t)(o[0] * inv); r[1] = (bf16_t)(o[1] * inv);
    r[2] = (bf16_t)(o[2] * inv); r[3] = (bf16_t)(o[3] * inv);
    *(bf16x4*)&AO[(size_t)m * DMODEL + c4] = r;
}

extern "C" void kernel_launch(void* const* d_in, const int* in_sizes, int n_in,
                              void* d_out, int out_size, void* d_ws, size_t ws_size,
                              hipStream_t stream) {
    (void)in_sizes; (void)n_in; (void)out_size; (void)ws_size;
    const float* x    = (const float*)d_in[0];
    const int*   pos  = (const int*)d_in[1];
    const float* qkvw = (const float*)d_in[2];
    const float* ow   = (const float*)d_in[3];
    float* out = (float*)d_out;

    const size_t HEAD_ELEMS = (size_t)BATCH * NHEADS * SEQ * DK;  // 4,194,304
    bf16_t* Qw  = (bf16_t*)d_ws;              // 8 MiB
    bf16_t* Kw  = Qw + HEAD_ELEMS;            // 8 MiB
    bf16_t* Vw  = Kw + HEAD_ELEMS;            // 8 MiB
    bf16_t* AO  = Vw + HEAD_ELEMS;            // 8 MiB — aliased with xb (disjoint live ranges)
    bf16_t* xb  = AO;
    bf16_t* wb  = AO + X_N;                   // 6 MiB
    bf16_t* ob  = wb + W_N;                   // 2 MiB
    float*  OAcc = (float*)(ob + O_N);        // 16 MiB fp32
    float*  LAcc = OAcc + (size_t)X_N;        // 256 KiB fp32  (total ~56.25 MiB)

    // 0) zero the attention accumulators (fp32 zeros == 0x0 bytes)
    hipMemsetAsync(OAcc, 0, (size_t)X_N * 4 + (size_t)BATCH * NHEADS * SEQ * 4, stream);
    // 1) fp32 -> bf16 for x, qkv_proj, o_proj
    convert_kernel<<<dim3(4096), 256, 0, stream>>>(x, qkvw, ow, xb, wb, ob);
    // 2) QKV projection + fused RoPE -> head-major bf16 Q/K/V
    qkv_gemm_kernel<<<dim3(24, 32), 256, 0, stream>>>(xb, wb, pos, Qw, Kw, Vw);
    // 3) split-K causal flash attention -> fp32 partials (OAcc, LAcc)
    attn_kernel<<<dim3(80, 32), 256, 0, stream>>>(Qw, Kw, Vw, OAcc, LAcc);
    // 4) normalize -> AO bf16
    norm_kernel<<<dim3(4096), 256, 0, stream>>>(OAcc, LAcc, AO);
    // 5) output projection -> fp32 d_out
    out_gemm_kernel<<<dim3(8, 32), 256, 0, stream>>>(AO, ob, out);
}

// Round 9
// 262.476 us; speedup vs baseline: 2.3785x; 2.3785x over previous
//
#include <hip/hip_runtime.h>
#include <hip/hip_bf16.h>
#include <math.h>

typedef __bf16 bf16_t;
typedef __attribute__((ext_vector_type(2))) __bf16 bf16x2;
typedef __attribute__((ext_vector_type(4))) __bf16 bf16x4;
typedef __attribute__((ext_vector_type(8))) __bf16 bf16x8;
typedef __attribute__((ext_vector_type(4))) float f32x4;

#define BATCH  2
#define SEQ    2048
#define DMODEL 1024
#define NHEADS 16
#define DK     64

typedef const __attribute__((address_space(1))) void* gas_t;
typedef __attribute__((address_space(3))) void* las_t;

// ---------------------------------------------------------------------------
// fp32 -> bf16 convert for x, qkv_proj, o_proj (8 elems/thread).
// ---------------------------------------------------------------------------
#define X_N (BATCH * SEQ * DMODEL)        // 4,194,304
#define W_N (3 * DMODEL * DMODEL)         // 3,145,728
#define O_N (DMODEL * DMODEL)             // 1,048,576

__global__ __launch_bounds__(256) void convert_kernel(
    const float* __restrict__ x, const float* __restrict__ w, const float* __restrict__ o,
    bf16_t* __restrict__ xb, bf16_t* __restrict__ wb, bf16_t* __restrict__ ob)
{
    const int gid = blockIdx.x * 256 + threadIdx.x;   // 1,048,576 threads
    const float* src; bf16_t* dst; int base = gid * 8;
    if (base < X_N)                { src = x; dst = xb; }
    else if (base < X_N + W_N)     { src = w; dst = wb; base -= X_N; }
    else                           { src = o; dst = ob; base -= X_N + W_N; }
    const f32x4 lo = *(const f32x4*)(src + base);
    const f32x4 hi = *(const f32x4*)(src + base + 4);
    bf16x8 r;
    r[0] = (bf16_t)lo[0]; r[1] = (bf16_t)lo[1]; r[2] = (bf16_t)lo[2]; r[3] = (bf16_t)lo[3];
    r[4] = (bf16_t)hi[0]; r[5] = (bf16_t)hi[1]; r[6] = (bf16_t)hi[2]; r[7] = (bf16_t)hi[3];
    *(bf16x8*)(dst + base) = r;
}

// ---------------------------------------------------------------------------
// m97-style 128x128 GEMM body (unchanged).
// ---------------------------------------------------------------------------
__device__ __forceinline__ void gemm128_body(
    const bf16_t* __restrict__ A, const bf16_t* __restrict__ B,
    int rowBase, int colBase, bf16_t* ldsA, bf16_t* ldsB, f32x4 acc[4][4])
{
    const int tid  = threadIdx.x;
    const int lane = tid & 63;
    const int l15  = lane & 15, quad = lane >> 4;
    const int qr   = ((tid >> 6) >> 1) * 64;
    const int qc   = ((tid >> 6) & 1) * 64;

    const int c0 = tid, c1 = tid + 256;
    const int r0 = c0 >> 2, kc0 = (c0 & 3) * 8;
    const int r1 = c1 >> 2, kc1 = (c1 & 3) * 8;
    const bf16_t* ga0 = A + (size_t)(rowBase + r0) * DMODEL + kc0;
    const bf16_t* ga1 = A + (size_t)(rowBase + r1) * DMODEL + kc1;
    const bf16_t* gb0 = B + (size_t)(colBase + r0) * DMODEL + kc0;
    const bf16_t* gb1 = B + (size_t)(colBase + r1) * DMODEL + kc1;

    for (int k0 = 0; k0 < DMODEL; k0 += 32) {
        __syncthreads();
        __builtin_amdgcn_global_load_lds((gas_t)(ga0 + k0), (las_t)(ldsA + c0 * 8), 16, 0, 0);
        __builtin_amdgcn_global_load_lds((gas_t)(ga1 + k0), (las_t)(ldsA + c1 * 8), 16, 0, 0);
        __builtin_amdgcn_global_load_lds((gas_t)(gb0 + k0), (las_t)(ldsB + c0 * 8), 16, 0, 0);
        __builtin_amdgcn_global_load_lds((gas_t)(gb1 + k0), (las_t)(ldsB + c1 * 8), 16, 0, 0);
        __syncthreads();

        bf16x8 af[4], bfr[4];
#pragma unroll
        for (int i = 0; i < 4; ++i)
            af[i] = *(const bf16x8*)&ldsA[(qr + i * 16 + l15) * 32 + quad * 8];
#pragma unroll
        for (int j = 0; j < 4; ++j)
            bfr[j] = *(const bf16x8*)&ldsB[(qc + j * 16 + l15) * 32 + quad * 8];
#pragma unroll
        for (int i = 0; i < 4; ++i)
#pragma unroll
            for (int j = 0; j < 4; ++j)
                acc[i][j] = __builtin_amdgcn_mfma_f32_16x16x32_bf16(af[i], bfr[j], acc[i][j], 0, 0, 0);
    }
}

// ---------------------------------------------------------------------------
// QKV GEMM with FUSED RoPE. v2: __sinf/__cosf (hardware sin/cos, inlined, no
// scratch) — R8's sincosf hit the Payne-Hanek OCML slow path, whose by-pointer
// results spilled to scratch: 1.4 GB of private-memory HBM writes, 430 us.
// ---------------------------------------------------------------------------
__global__ __launch_bounds__(256) void qkv_gemm_kernel(
    const bf16_t* __restrict__ x, const bf16_t* __restrict__ w,
    const int* __restrict__ pos,
    bf16_t* __restrict__ qo, bf16_t* __restrict__ ko, bf16_t* __restrict__ vo)
{
    __shared__ bf16_t ldsA[128 * 32];
    __shared__ bf16_t ldsB[128 * 32];
    const int rowBase = blockIdx.y * 128;
    const int colBase = blockIdx.x * 128;
    f32x4 acc[4][4] = {};
    gemm128_body(x, w, rowBase, colBase, ldsA, ldsB, acc);

    const int lane = threadIdx.x & 63;
    const int l15 = lane & 15, quad = lane >> 4;
    const int qr = ((threadIdx.x >> 6) >> 1) * 64;
    const int qc = ((threadIdx.x >> 6) & 1) * 64;
#pragma unroll
    for (int j = 0; j < 4; ++j) {
        const int col  = colBase + qc + j * 16 + l15;
        const int part = col >> 10;             // wave-uniform (l15 < 16)
        const int h    = (col & 1023) >> 6;
        const int d    = col & 63;
        bf16_t* op = (part == 0) ? qo : (part == 1) ? ko : vo;
        if (part < 2) {
            // theta^(-2*(d>>1)/64) = 2^(-(d>>1) * 2*log2(1e4)/64)
            const float invf  = exp2f(-(float)(d >> 1) * 0.4152410118609203f);
            const float psign = (d & 1) ? 1.f : -1.f;
#pragma unroll
            for (int i = 0; i < 4; ++i) {
#pragma unroll
                for (int r = 0; r < 4; ++r) {
                    const int m = rowBase + qr + i * 16 + quad * 4 + r;
                    const int b = m >> 11;
                    const int s = m & (SEQ - 1);
                    const float ang = (float)pos[s] * invf;
                    const float sn_ = __sinf(ang);   // v_sin_f32, no scratch
                    const float c_  = __cosf(ang);   // v_cos_f32, no scratch
                    const float v = acc[i][j][r];
                    const float p = __shfl_xor(v, 1);
                    const float res = fmaf(p, psign * sn_, v * c_);
                    op[((size_t)(b * NHEADS + h) * SEQ + s) * DK + d] = (bf16_t)res;
                }
            }
        } else {
#pragma unroll
            for (int i = 0; i < 4; ++i) {
#pragma unroll
                for (int r = 0; r < 4; ++r) {
                    const int m = rowBase + qr + i * 16 + quad * 4 + r;
                    const int b = m >> 11;
                    const int s = m & (SEQ - 1);
                    op[((size_t)(b * NHEADS + h) * SEQ + s) * DK + d] = (bf16_t)acc[i][j][r];
                }
            }
        }
    }
}

// Output GEMM: M=4096, N=1024, fp32 direct-store epilogue.
__global__ __launch_bounds__(256) void out_gemm_kernel(
    const bf16_t* __restrict__ a, const bf16_t* __restrict__ w, float* __restrict__ out)
{
    __shared__ bf16_t ldsA[128 * 32];
    __shared__ bf16_t ldsB[128 * 32];
    const int rowBase = blockIdx.y * 128;
    const int colBase = blockIdx.x * 128;
    f32x4 acc[4][4] = {};
    gemm128_body(a, w, rowBase, colBase, ldsA, ldsB, acc);

    const int lane = threadIdx.x & 63;
    const int l15 = lane & 15, quad = lane >> 4;
    const int qr = ((threadIdx.x >> 6) >> 1) * 64;
    const int qc = ((threadIdx.x >> 6) & 1) * 64;
#pragma unroll
    for (int i = 0; i < 4; ++i) {
#pragma unroll
        for (int r = 0; r < 4; ++r) {
            const int m = rowBase + qr + i * 16 + quad * 4 + r;
#pragma unroll
            for (int j = 0; j < 4; ++j)
                out[(size_t)m * DMODEL + colBase + qc + j * 16 + l15] = acc[i][j][r];
        }
    }
}

// ---------------------------------------------------------------------------
// Split-K flash attention (unchanged from R8; attn dropped out of top-5).
// ---------------------------------------------------------------------------
__global__ __launch_bounds__(256) void attn_kernel(
    const bf16_t* __restrict__ Q, const bf16_t* __restrict__ K,
    const bf16_t* __restrict__ V,
    float* __restrict__ OAcc, float* __restrict__ LAcc)
{
    __shared__ bf16_t Vt[2][64 * 72];    // [buf][d][pos], stride 72, swizzled
    __shared__ bf16_t Pb[4][16 * 72];    // per-wave P, [q][pos], stride 72

    const int bh = blockIdx.y;                   // 0..31
    // x -> (qblk, chunk); reversed so 8-tile chunks dispatch first
    const int x = 79 - blockIdx.x;
    int qblk, chunk;
    if (x < 8)       { qblk = x;                  chunk = 0; }
    else if (x < 24) { qblk = 8  + ((x - 8) >> 1);  chunk = (x - 8) & 1; }
    else if (x < 48) { qblk = 16 + (x - 24) / 3;    chunk = (x - 24) % 3; }
    else             { qblk = 24 + ((x - 48) >> 2); chunk = (x - 48) & 3; }
    const int kb0 = chunk * 8;
    const int kbe = min(qblk + 1, kb0 + 8);      // exclusive tile end

    const int tid  = threadIdx.x;
    const int wave = tid >> 6, lane = tid & 63;
    const int l15  = lane & 15, quad = lane >> 4;
    const int q0   = qblk * 64 + wave * 16;
    const size_t hb = (size_t)bh * SEQ * DK;

    // Q fragments, pre-scaled by 1/8 (exact in bf16)
    const bf16_t* qrow = Q + hb + (size_t)(q0 + l15) * DK + quad * 8;
    bf16x8 aq0 = *(const bf16x8*)qrow;
    bf16x8 aq1 = *(const bf16x8*)(qrow + 32);
#pragma unroll
    for (int i = 0; i < 8; ++i) {
        aq0[i] = (bf16_t)((float)aq0[i] * 0.125f);
        aq1[i] = (bf16_t)((float)aq1[i] * 0.125f);
    }

    f32x4 oacc[4] = {};
    float lsum[4] = {0.f, 0.f, 0.f, 0.f};

    // V staging task: thread (cgi, rr) stages d-group cgi of key rows k1, k1+16
    const int cgi = tid & 7;
    const int rr  = tid >> 3;
    const int k1  = (rr & 15) + ((rr >> 4) << 5);
    const int vpos = ((k1 & 15) << 2) + (k1 >> 4);        // even
    const int vsw  = vpos ^ (cgi << 3);                   // swizzled, still even
    const bf16_t* vst_g = V + hb + k1 * 64 + cgi * 8;
    const bf16_t* kfr_g = K + hb + l15 * 64 + quad * 8;   // B[k=d][n=key]

    // ---- prologue: tile kb0 -> K regs + Vt[kb0&1] ----
    bf16x8 kf0[4], kf1[4];
    {
        const bf16_t* kg = kfr_g + (size_t)kb0 * 4096;
#pragma unroll
        for (int c = 0; c < 4; ++c) {
            kf0[c] = *(const bf16x8*)(kg + c * 1024);
            kf1[c] = *(const bf16x8*)(kg + c * 1024 + 32);
        }
        const bf16x8 v1 = *(const bf16x8*)(vst_g + (size_t)kb0 * 4096);
        const bf16x8 v2 = *(const bf16x8*)(vst_g + (size_t)kb0 * 4096 + 1024);
#pragma unroll
        for (int j = 0; j < 8; ++j)
            *(bf16x2*)&Vt[kb0 & 1][(cgi * 8 + j) * 72 + vsw] = (bf16x2){v1[j], v2[j]};
    }

    for (int kb = kb0; kb < kbe; ++kb) {
        const int buf = kb & 1;
        __syncthreads();   // Vt[buf] staged; prior reads of Vt[buf^1] done

        // ---- prefetch tile kb+1 into regs ----
        const bool pf = (kb + 1 < kbe);
        bf16x8 kn0[4], kn1[4], v1n, v2n;
        if (pf) {
            const bf16_t* kg = kfr_g + (size_t)(kb + 1) * 4096;
#pragma unroll
            for (int c = 0; c < 4; ++c) {
                kn0[c] = *(const bf16x8*)(kg + c * 1024);
                kn1[c] = *(const bf16x8*)(kg + c * 1024 + 32);
            }
            v1n = *(const bf16x8*)(vst_g + (size_t)(kb + 1) * 4096);
            v2n = *(const bf16x8*)(vst_g + (size_t)(kb + 1) * 4096 + 1024);
        }

        // ---- scores: S = (Q/8) . K^T, K operands in registers ----
        const bool diag = (kb == qblk);
        f32x4 sc[4];
#pragma unroll
        for (int c = 0; c < 4; ++c) {
            f32x4 z = {};
            z = __builtin_amdgcn_mfma_f32_16x16x32_bf16(aq0, kf0[c], z, 0, 0, 0);
            z = __builtin_amdgcn_mfma_f32_16x16x32_bf16(aq1, kf1[c], z, 0, 0, 0);
            sc[c] = z;
        }

        // ---- p = exp(s - 8); packed b64 P store in permuted key order ----
#pragma unroll
        for (int r = 0; r < 4; ++r) {
            bf16x4 pr;
#pragma unroll
            for (int c = 0; c < 4; ++c) {
                float s = sc[c][r];
                if (diag) {
                    const int key = kb * 64 + c * 16 + l15;
                    const int qa  = q0 + quad * 4 + r;
                    s = (key <= qa) ? s : -INFINITY;
                }
                const float p = __expf(s - 8.0f);
                lsum[r] += p;
                pr[c] = (bf16_t)p;
            }
            *(bf16x4*)&Pb[wave][(quad * 4 + r) * 72 + l15 * 4] = pr;
        }
        asm volatile("s_waitcnt lgkmcnt(0)" ::: "memory");  // wave-private LDS RAW
        const bf16x8 ap0 = *(const bf16x8*)&Pb[wave][l15 * 72 + quad * 8];
        const bf16x8 ap1 = *(const bf16x8*)&Pb[wave][l15 * 72 + 32 + quad * 8];

        // ---- O += P . V ----
#pragma unroll
        for (int t = 0; t < 4; ++t) {
            const int dd = t * 2 + (l15 >> 3);
            const bf16_t* vrow = &Vt[buf][(t * 16 + l15) * 72];
            const bf16x8 bv0 = *(const bf16x8*)(vrow + ((quad ^ dd) << 3));
            const bf16x8 bv1 = *(const bf16x8*)(vrow + (((4 + quad) ^ dd) << 3));
            oacc[t] = __builtin_amdgcn_mfma_f32_16x16x32_bf16(ap0, bv0, oacc[t], 0, 0, 0);
            oacc[t] = __builtin_amdgcn_mfma_f32_16x16x32_bf16(ap1, bv1, oacc[t], 0, 0, 0);
        }

        // ---- commit prefetch ----
        if (pf) {
#pragma unroll
            for (int c = 0; c < 4; ++c) { kf0[c] = kn0[c]; kf1[c] = kn1[c]; }
#pragma unroll
            for (int j = 0; j < 8; ++j)
                *(bf16x2*)&Vt[buf ^ 1][(cgi * 8 + j) * 72 + vsw] = (bf16x2){v1n[j], v2n[j]};
        }
    }

    // ---- partial epilogue: atomically accumulate (O, l) in fp32 ----
    const int b = bh >> 4, h = bh & 15;
#pragma unroll
    for (int r = 0; r < 4; ++r) {
        float s = lsum[r];
        s += __shfl_xor(s, 1);
        s += __shfl_xor(s, 2);
        s += __shfl_xor(s, 4);
        s += __shfl_xor(s, 8);
        if (l15 == 0)
            unsafeAtomicAdd(&LAcc[(size_t)bh * SEQ + (q0 + quad * 4 + r)], s);
    }
#pragma unroll
    for (int t = 0; t < 4; ++t) {
#pragma unroll
        for (int r = 0; r < 4; ++r) {
            const int qa = q0 + quad * 4 + r;
            unsafeAtomicAdd(&OAcc[(size_t)(b * SEQ + qa) * DMODEL + h * 64 + t * 16 + l15],
                            oacc[t][r]);
        }
    }
}

// ---------------------------------------------------------------------------
// Normalize: AO_bf16 = OAcc / LAcc  (4 elems/thread).
// ---------------------------------------------------------------------------
__global__ __launch_bounds__(256) void norm_kernel(
    const float* __restrict__ OAcc, const float* __restrict__ LAcc,
    bf16_t* __restrict__ AO)
{
    const int gid = blockIdx.x * 256 + threadIdx.x;   // 1,048,576 threads
    const int m  = gid >> 8;
    const int c4 = (gid & 255) * 4;
    const int h  = c4 >> 6;
    const int b  = m >> 11;
    const int s  = m & (SEQ - 1);
    const float inv = 1.0f / LAcc[(size_t)(b * NHEADS + h) * SEQ + s];
    const f32x4 o = *(const f32x4*)&OAcc[(size_t)m * DMODEL + c4];
    bf16x4 r;
    r[0] = (bf16_t)(o[0] * inv); r[1] = (bf16_t)(o[1] * inv);
    r[2] = (bf16_t)(o[2] * inv); r[3] = (bf16_t)(o[3] * inv);
    *(bf16x4*)&AO[(size_t)m * DMODEL + c4] = r;
}

extern "C" void kernel_launch(void* const* d_in, const int* in_sizes, int n_in,
                              void* d_out, int out_size, void* d_ws, size_t ws_size,
                              hipStream_t stream) {
    (void)in_sizes; (void)n_in; (void)out_size; (void)ws_size;
    const float* x    = (const float*)d_in[0];
    const int*   pos  = (const int*)d_in[1];
    const float* qkvw = (const float*)d_in[2];
    const float* ow   = (const float*)d_in[3];
    float* out = (float*)d_out;

    const size_t HEAD_ELEMS = (size_t)BATCH * NHEADS * SEQ * DK;  // 4,194,304
    bf16_t* Qw  = (bf16_t*)d_ws;              // 8 MiB
    bf16_t* Kw  = Qw + HEAD_ELEMS;            // 8 MiB
    bf16_t* Vw  = Kw + HEAD_ELEMS;            // 8 MiB
    bf16_t* AO  = Vw + HEAD_ELEMS;            // 8 MiB — aliased with xb (disjoint live ranges)
    bf16_t* xb  = AO;
    bf16_t* wb  = AO + X_N;                   // 6 MiB
    bf16_t* ob  = wb + W_N;                   // 2 MiB
    float*  OAcc = (float*)(ob + O_N);        // 16 MiB fp32
    float*  LAcc = OAcc + (size_t)X_N;        // 256 KiB fp32  (total ~56.25 MiB)

    // 0) zero the attention accumulators (fp32 zeros == 0x0 bytes)
    hipMemsetAsync(OAcc, 0, (size_t)X_N * 4 + (size_t)BATCH * NHEADS * SEQ * 4, stream);
    // 1) fp32 -> bf16 for x, qkv_proj, o_proj
    convert_kernel<<<dim3(4096), 256, 0, stream>>>(x, qkvw, ow, xb, wb, ob);
    // 2) QKV projection + fused RoPE -> head-major bf16 Q/K/V
    qkv_gemm_kernel<<<dim3(24, 32), 256, 0, stream>>>(xb, wb, pos, Qw, Kw, Vw);
    // 3) split-K causal flash attention -> fp32 partials (OAcc, LAcc)
    attn_kernel<<<dim3(80, 32), 256, 0, stream>>>(Qw, Kw, Vw, OAcc, LAcc);
    // 4) normalize -> AO bf16
    norm_kernel<<<dim3(4096), 256, 0, stream>>>(OAcc, LAcc, AO);
    // 5) output projection -> fp32 d_out
    out_gemm_kernel<<<dim3(8, 32), 256, 0, stream>>>(AO, ob, out);
}

// Round 10
// 245.019 us; speedup vs baseline: 2.5480x; 1.0713x over previous
//
#include <hip/hip_runtime.h>
#include <hip/hip_bf16.h>
#include <math.h>

typedef __bf16 bf16_t;
typedef __attribute__((ext_vector_type(2))) __bf16 bf16x2;
typedef __attribute__((ext_vector_type(4))) __bf16 bf16x4;
typedef __attribute__((ext_vector_type(8))) __bf16 bf16x8;
typedef __attribute__((ext_vector_type(4))) float f32x4;

#define BATCH  2
#define SEQ    2048
#define DMODEL 1024
#define NHEADS 16
#define DK     64

typedef const __attribute__((address_space(1))) void* gas_t;
typedef __attribute__((address_space(3))) void* las_t;

#define X_N (BATCH * SEQ * DMODEL)        // 4,194,304
#define W_N (3 * DMODEL * DMODEL)         // 3,145,728
#define O_N (DMODEL * DMODEL)             // 1,048,576

__global__ __launch_bounds__(256) void convert_kernel(
    const float* __restrict__ x, const float* __restrict__ w, const float* __restrict__ o,
    bf16_t* __restrict__ xb, bf16_t* __restrict__ wb, bf16_t* __restrict__ ob)
{
    const int gid = blockIdx.x * 256 + threadIdx.x;   // 1,048,576 threads
    const float* src; bf16_t* dst; int base = gid * 8;
    if (base < X_N)                { src = x; dst = xb; }
    else if (base < X_N + W_N)     { src = w; dst = wb; base -= X_N; }
    else                           { src = o; dst = ob; base -= X_N + W_N; }
    const f32x4 lo = *(const f32x4*)(src + base);
    const f32x4 hi = *(const f32x4*)(src + base + 4);
    bf16x8 r;
    r[0] = (bf16_t)lo[0]; r[1] = (bf16_t)lo[1]; r[2] = (bf16_t)lo[2]; r[3] = (bf16_t)lo[3];
    r[4] = (bf16_t)hi[0]; r[5] = (bf16_t)hi[1]; r[6] = (bf16_t)hi[2]; r[7] = (bf16_t)hi[3];
    *(bf16x8*)(dst + base) = r;
}

// ---------------------------------------------------------------------------
// m97-style 128x128 GEMM body (qkv only).
// ---------------------------------------------------------------------------
__device__ __forceinline__ void gemm128_body(
    const bf16_t* __restrict__ A, const bf16_t* __restrict__ B,
    int rowBase, int colBase, bf16_t* ldsA, bf16_t* ldsB, f32x4 acc[4][4])
{
    const int tid  = threadIdx.x;
    const int lane = tid & 63;
    const int l15  = lane & 15, quad = lane >> 4;
    const int qr   = ((tid >> 6) >> 1) * 64;
    const int qc   = ((tid >> 6) & 1) * 64;

    const int c0 = tid, c1 = tid + 256;
    const int r0 = c0 >> 2, kc0 = (c0 & 3) * 8;
    const int r1 = c1 >> 2, kc1 = (c1 & 3) * 8;
    const bf16_t* ga0 = A + (size_t)(rowBase + r0) * DMODEL + kc0;
    const bf16_t* ga1 = A + (size_t)(rowBase + r1) * DMODEL + kc1;
    const bf16_t* gb0 = B + (size_t)(colBase + r0) * DMODEL + kc0;
    const bf16_t* gb1 = B + (size_t)(colBase + r1) * DMODEL + kc1;

    for (int k0 = 0; k0 < DMODEL; k0 += 32) {
        __syncthreads();
        __builtin_amdgcn_global_load_lds((gas_t)(ga0 + k0), (las_t)(ldsA + c0 * 8), 16, 0, 0);
        __builtin_amdgcn_global_load_lds((gas_t)(ga1 + k0), (las_t)(ldsA + c1 * 8), 16, 0, 0);
        __builtin_amdgcn_global_load_lds((gas_t)(gb0 + k0), (las_t)(ldsB + c0 * 8), 16, 0, 0);
        __builtin_amdgcn_global_load_lds((gas_t)(gb1 + k0), (las_t)(ldsB + c1 * 8), 16, 0, 0);
        __syncthreads();

        bf16x8 af[4], bfr[4];
#pragma unroll
        for (int i = 0; i < 4; ++i)
            af[i] = *(const bf16x8*)&ldsA[(qr + i * 16 + l15) * 32 + quad * 8];
#pragma unroll
        for (int j = 0; j < 4; ++j)
            bfr[j] = *(const bf16x8*)&ldsB[(qc + j * 16 + l15) * 32 + quad * 8];
#pragma unroll
        for (int i = 0; i < 4; ++i)
#pragma unroll
            for (int j = 0; j < 4; ++j)
                acc[i][j] = __builtin_amdgcn_mfma_f32_16x16x32_bf16(af[i], bfr[j], acc[i][j], 0, 0, 0);
    }
}

// ---------------------------------------------------------------------------
// QKV GEMM with fused RoPE (__sinf/__cosf — R9-verified, no scratch).
// ---------------------------------------------------------------------------
__global__ __launch_bounds__(256) void qkv_gemm_kernel(
    const bf16_t* __restrict__ x, const bf16_t* __restrict__ w,
    const int* __restrict__ pos,
    bf16_t* __restrict__ qo, bf16_t* __restrict__ ko, bf16_t* __restrict__ vo)
{
    __shared__ bf16_t ldsA[128 * 32];
    __shared__ bf16_t ldsB[128 * 32];
    const int rowBase = blockIdx.y * 128;
    const int colBase = blockIdx.x * 128;
    f32x4 acc[4][4] = {};
    gemm128_body(x, w, rowBase, colBase, ldsA, ldsB, acc);

    const int lane = threadIdx.x & 63;
    const int l15 = lane & 15, quad = lane >> 4;
    const int qr = ((threadIdx.x >> 6) >> 1) * 64;
    const int qc = ((threadIdx.x >> 6) & 1) * 64;
#pragma unroll
    for (int j = 0; j < 4; ++j) {
        const int col  = colBase + qc + j * 16 + l15;
        const int part = col >> 10;             // wave-uniform
        const int h    = (col & 1023) >> 6;
        const int d    = col & 63;
        bf16_t* op = (part == 0) ? qo : (part == 1) ? ko : vo;
        if (part < 2) {
            const float invf  = exp2f(-(float)(d >> 1) * 0.4152410118609203f);
            const float psign = (d & 1) ? 1.f : -1.f;
#pragma unroll
            for (int i = 0; i < 4; ++i) {
#pragma unroll
                for (int r = 0; r < 4; ++r) {
                    const int m = rowBase + qr + i * 16 + quad * 4 + r;
                    const int b = m >> 11;
                    const int s = m & (SEQ - 1);
                    const float ang = (float)pos[s] * invf;
                    const float sn_ = __sinf(ang);
                    const float c_  = __cosf(ang);
                    const float v = acc[i][j][r];
                    const float p = __shfl_xor(v, 1);
                    const float res = fmaf(p, psign * sn_, v * c_);
                    op[((size_t)(b * NHEADS + h) * SEQ + s) * DK + d] = (bf16_t)res;
                }
            }
        } else {
#pragma unroll
            for (int i = 0; i < 4; ++i) {
#pragma unroll
                for (int r = 0; r < 4; ++r) {
                    const int m = rowBase + qr + i * 16 + quad * 4 + r;
                    const int b = m >> 11;
                    const int s = m & (SEQ - 1);
                    op[((size_t)(b * NHEADS + h) * SEQ + s) * DK + d] = (bf16_t)acc[i][j][r];
                }
            }
        }
    }
}

// ---------------------------------------------------------------------------
// Output GEMM v2: 128x64 tiles -> grid 512 blocks (2/CU; the 128x128 version
// was 256 blocks = exactly 1/CU, zero inter-block latency hiding).
// Wave w: 32 rows x 64 cols (acc[2][4]).
// ---------------------------------------------------------------------------
__global__ __launch_bounds__(256) void out_gemm_kernel(
    const bf16_t* __restrict__ a, const bf16_t* __restrict__ w, float* __restrict__ out)
{
    __shared__ bf16_t ldsA[128 * 32];
    __shared__ bf16_t ldsB[64 * 32];
    const int tid  = threadIdx.x;
    const int lane = tid & 63;
    const int l15  = lane & 15, quad = lane >> 4;
    const int wv   = tid >> 6;
    const int rowBase = blockIdx.y * 128;
    const int colBase = blockIdx.x * 64;

    const int c0 = tid, c1 = tid + 256;
    const bf16_t* ga0 = a + (size_t)(rowBase + (c0 >> 2)) * DMODEL + (c0 & 3) * 8;
    const bf16_t* ga1 = a + (size_t)(rowBase + (c1 >> 2)) * DMODEL + (c1 & 3) * 8;
    const bf16_t* gb0 = w + (size_t)(colBase + (tid >> 2)) * DMODEL + (tid & 3) * 8;

    f32x4 acc[2][4] = {};
    for (int k0 = 0; k0 < DMODEL; k0 += 32) {
        __syncthreads();
        __builtin_amdgcn_global_load_lds((gas_t)(ga0 + k0), (las_t)(ldsA + c0 * 8), 16, 0, 0);
        __builtin_amdgcn_global_load_lds((gas_t)(ga1 + k0), (las_t)(ldsA + c1 * 8), 16, 0, 0);
        __builtin_amdgcn_global_load_lds((gas_t)(gb0 + k0), (las_t)(ldsB + tid * 8), 16, 0, 0);
        __syncthreads();

        bf16x8 af[2], bfr[4];
#pragma unroll
        for (int i = 0; i < 2; ++i)
            af[i] = *(const bf16x8*)&ldsA[(wv * 32 + i * 16 + l15) * 32 + quad * 8];
#pragma unroll
        for (int j = 0; j < 4; ++j)
            bfr[j] = *(const bf16x8*)&ldsB[(j * 16 + l15) * 32 + quad * 8];
#pragma unroll
        for (int i = 0; i < 2; ++i)
#pragma unroll
            for (int j = 0; j < 4; ++j)
                acc[i][j] = __builtin_amdgcn_mfma_f32_16x16x32_bf16(af[i], bfr[j], acc[i][j], 0, 0, 0);
    }
#pragma unroll
    for (int i = 0; i < 2; ++i) {
#pragma unroll
        for (int r = 0; r < 4; ++r) {
            const int m = rowBase + wv * 32 + i * 16 + quad * 4 + r;
#pragma unroll
            for (int j = 0; j < 4; ++j)
                out[(size_t)m * DMODEL + colBase + j * 16 + l15] = acc[i][j][r];
        }
    }
}

// ---------------------------------------------------------------------------
// Split-K flash attention v6: 128-query blocks, 32 queries/wave (2 fragments).
// Halves wave-tiles vs v5; V LDS reads / K prefetch / barriers / commit are
// shared across both fragments. Static heavy-first schedule (40 chunks/bh).
// ---------------------------------------------------------------------------
__device__ __constant__ unsigned char SCHED[40] = {
    12,16,20,24,28,29,32,33,36,37,40,41,44,45,46,48,49,50,52,53,54,56,57,58,
    60,61,62,63,              // 8-tile chunks
    8,25,42,59,               // 6-tile
    4,21,38,55,               // 4-tile
    0,17,34,51 };             // 2-tile   (byte = qblk*4 + chunk)

__global__ __launch_bounds__(256) void attn_kernel(
    const bf16_t* __restrict__ Q, const bf16_t* __restrict__ K,
    const bf16_t* __restrict__ V,
    float* __restrict__ OAcc, float* __restrict__ LAcc)
{
    __shared__ bf16_t Vt[2][64 * 72];    // [buf][d][pos], stride 72, swizzled
    __shared__ bf16_t Pb[4][32 * 72];    // per-wave P, rows = 16f + quad*4+r

    const int bh = blockIdx.y;                   // 0..31
    const int e  = SCHED[blockIdx.x];
    const int qblk = e >> 2, chunk = e & 3;      // qblk of 128 queries
    const int kb0 = chunk * 8;
    const int kbe = min(2 * qblk + 2, kb0 + 8);  // exclusive 64-key tile end

    const int tid  = threadIdx.x;
    const int wave = tid >> 6, lane = tid & 63;
    const int l15  = lane & 15, quad = lane >> 4;
    const int q0   = qblk * 128 + wave * 32;     // wave's 32 queries
    const size_t hb = (size_t)bh * SEQ * DK;

    // Q fragments (f = 0,1 -> queries q0+16f..+15), pre-scaled by 1/8
    bf16x8 aq0[2], aq1[2];
#pragma unroll
    for (int f = 0; f < 2; ++f) {
        const bf16_t* qrow = Q + hb + (size_t)(q0 + 16 * f + l15) * DK + quad * 8;
        aq0[f] = *(const bf16x8*)qrow;
        aq1[f] = *(const bf16x8*)(qrow + 32);
#pragma unroll
        for (int i = 0; i < 8; ++i) {
            aq0[f][i] = (bf16_t)((float)aq0[f][i] * 0.125f);
            aq1[f][i] = (bf16_t)((float)aq1[f][i] * 0.125f);
        }
    }

    f32x4 oacc[2][4] = {};
    float lsum[2][4] = {};

    // V staging task (thread stages d-group cgi of key rows k1, k1+16)
    const int cgi = tid & 7;
    const int rr  = tid >> 3;
    const int k1  = (rr & 15) + ((rr >> 4) << 5);
    const int vpos = ((k1 & 15) << 2) + (k1 >> 4);
    const int vsw  = vpos ^ (cgi << 3);
    const bf16_t* vst_g = V + hb + k1 * 64 + cgi * 8;
    const bf16_t* kfr_g = K + hb + l15 * 64 + quad * 8;   // B[k=d][n=key]

    // ---- prologue: tile kb0 -> K regs + Vt[kb0&1] ----
    bf16x8 kf0[4], kf1[4];
    {
        const bf16_t* kg = kfr_g + (size_t)kb0 * 4096;
#pragma unroll
        for (int c = 0; c < 4; ++c) {
            kf0[c] = *(const bf16x8*)(kg + c * 1024);
            kf1[c] = *(const bf16x8*)(kg + c * 1024 + 32);
        }
        const bf16x8 v1 = *(const bf16x8*)(vst_g + (size_t)kb0 * 4096);
        const bf16x8 v2 = *(const bf16x8*)(vst_g + (size_t)kb0 * 4096 + 1024);
#pragma unroll
        for (int j = 0; j < 8; ++j)
            *(bf16x2*)&Vt[kb0 & 1][(cgi * 8 + j) * 72 + vsw] = (bf16x2){v1[j], v2[j]};
    }

    for (int kb = kb0; kb < kbe; ++kb) {
        const int buf = kb & 1;
        __syncthreads();   // Vt[buf] staged; prior reads of Vt[buf^1] done

        // ---- prefetch tile kb+1 into regs ----
        const bool pf = (kb + 1 < kbe);
        bf16x8 kn0[4], kn1[4], v1n, v2n;
        if (pf) {
            const bf16_t* kg = kfr_g + (size_t)(kb + 1) * 4096;
#pragma unroll
            for (int c = 0; c < 4; ++c) {
                kn0[c] = *(const bf16x8*)(kg + c * 1024);
                kn1[c] = *(const bf16x8*)(kg + c * 1024 + 32);
            }
            v1n = *(const bf16x8*)(vst_g + (size_t)(kb + 1) * 4096);
            v2n = *(const bf16x8*)(vst_g + (size_t)(kb + 1) * 4096 + 1024);
        }

        // ---- per fragment: QK scores + exp + packed P store ----
        bool act[2];
#pragma unroll
        for (int f = 0; f < 2; ++f) {
            act[f] = (kb * 64 <= q0 + 16 * f + 15);      // wave-uniform
            if (act[f]) {
                f32x4 sc[4];
#pragma unroll
                for (int c = 0; c < 4; ++c) {
                    f32x4 z = {};
                    z = __builtin_amdgcn_mfma_f32_16x16x32_bf16(aq0[f], kf0[c], z, 0, 0, 0);
                    z = __builtin_amdgcn_mfma_f32_16x16x32_bf16(aq1[f], kf1[c], z, 0, 0, 0);
                    sc[c] = z;
                }
                const bool needmask = (kb * 64 + 63 > q0 + 16 * f);   // wave-uniform
#pragma unroll
                for (int r = 0; r < 4; ++r) {
                    bf16x4 pr;
#pragma unroll
                    for (int c = 0; c < 4; ++c) {
                        float s = sc[c][r];
                        if (needmask) {
                            const int key = kb * 64 + c * 16 + l15;
                            const int qa  = q0 + 16 * f + quad * 4 + r;
                            s = (key <= qa) ? s : -INFINITY;
                        }
                        const float p = __expf(s - 8.0f);
                        lsum[f][r] += p;
                        pr[c] = (bf16_t)p;
                    }
                    *(bf16x4*)&Pb[wave][(16 * f + quad * 4 + r) * 72 + l15 * 4] = pr;
                }
            }
        }
        asm volatile("s_waitcnt lgkmcnt(0)" ::: "memory");  // wave-private LDS RAW

        bf16x8 ap0[2], ap1[2];
#pragma unroll
        for (int f = 0; f < 2; ++f) {
            if (act[f]) {
                ap0[f] = *(const bf16x8*)&Pb[wave][(16 * f + l15) * 72 + quad * 8];
                ap1[f] = *(const bf16x8*)&Pb[wave][(16 * f + l15) * 72 + 32 + quad * 8];
            }
        }

        // ---- O += P.V : V reads shared across both fragments ----
#pragma unroll
        for (int t = 0; t < 4; ++t) {
            const int dd = t * 2 + (l15 >> 3);
            const bf16_t* vrow = &Vt[buf][(t * 16 + l15) * 72];
            const bf16x8 bv0 = *(const bf16x8*)(vrow + ((quad ^ dd) << 3));
            const bf16x8 bv1 = *(const bf16x8*)(vrow + (((4 + quad) ^ dd) << 3));
#pragma unroll
            for (int f = 0; f < 2; ++f) {
                if (act[f]) {
                    oacc[f][t] = __builtin_amdgcn_mfma_f32_16x16x32_bf16(ap0[f], bv0, oacc[f][t], 0, 0, 0);
                    oacc[f][t] = __builtin_amdgcn_mfma_f32_16x16x32_bf16(ap1[f], bv1, oacc[f][t], 0, 0, 0);
                }
            }
        }

        // ---- commit prefetch ----
        if (pf) {
#pragma unroll
            for (int c = 0; c < 4; ++c) { kf0[c] = kn0[c]; kf1[c] = kn1[c]; }
#pragma unroll
            for (int j = 0; j < 8; ++j)
                *(bf16x2*)&Vt[buf ^ 1][(cgi * 8 + j) * 72 + vsw] = (bf16x2){v1n[j], v2n[j]};
        }
    }

    // ---- partial epilogue: atomically accumulate (O, l) in fp32 ----
    const int b = bh >> 4, h = bh & 15;
#pragma unroll
    for (int f = 0; f < 2; ++f) {
#pragma unroll
        for (int r = 0; r < 4; ++r) {
            float s = lsum[f][r];
            s += __shfl_xor(s, 1);
            s += __shfl_xor(s, 2);
            s += __shfl_xor(s, 4);
            s += __shfl_xor(s, 8);
            if (l15 == 0)
                unsafeAtomicAdd(&LAcc[(size_t)bh * SEQ + (q0 + 16 * f + quad * 4 + r)], s);
        }
#pragma unroll
        for (int t = 0; t < 4; ++t) {
#pragma unroll
            for (int r = 0; r < 4; ++r) {
                const int qa = q0 + 16 * f + quad * 4 + r;
                unsafeAtomicAdd(&OAcc[(size_t)(b * SEQ + qa) * DMODEL + h * 64 + t * 16 + l15],
                                oacc[f][t][r]);
            }
        }
    }
}

// ---------------------------------------------------------------------------
// Normalize: AO_bf16 = OAcc / LAcc  (4 elems/thread).
// ---------------------------------------------------------------------------
__global__ __launch_bounds__(256) void norm_kernel(
    const float* __restrict__ OAcc, const float* __restrict__ LAcc,
    bf16_t* __restrict__ AO)
{
    const int gid = blockIdx.x * 256 + threadIdx.x;   // 1,048,576 threads
    const int m  = gid >> 8;
    const int c4 = (gid & 255) * 4;
    const int h  = c4 >> 6;
    const int b  = m >> 11;
    const int s  = m & (SEQ - 1);
    const float inv = 1.0f / LAcc[(size_t)(b * NHEADS + h) * SEQ + s];
    const f32x4 o = *(const f32x4*)&OAcc[(size_t)m * DMODEL + c4];
    bf16x4 r;
    r[0] = (bf16_t)(o[0] * inv); r[1] = (bf16_t)(o[1] * inv);
    r[2] = (bf16_t)(o[2] * inv); r[3] = (bf16_t)(o[3] * inv);
    *(bf16x4*)&AO[(size_t)m * DMODEL + c4] = r;
}

extern "C" void kernel_launch(void* const* d_in, const int* in_sizes, int n_in,
                              void* d_out, int out_size, void* d_ws, size_t ws_size,
                              hipStream_t stream) {
    (void)in_sizes; (void)n_in; (void)out_size; (void)ws_size;
    const float* x    = (const float*)d_in[0];
    const int*   pos  = (const int*)d_in[1];
    const float* qkvw = (const float*)d_in[2];
    const float* ow   = (const float*)d_in[3];
    float* out = (float*)d_out;

    const size_t HEAD_ELEMS = (size_t)BATCH * NHEADS * SEQ * DK;  // 4,194,304
    bf16_t* Qw  = (bf16_t*)d_ws;              // 8 MiB
    bf16_t* Kw  = Qw + HEAD_ELEMS;            // 8 MiB
    bf16_t* Vw  = Kw + HEAD_ELEMS;            // 8 MiB
    bf16_t* AO  = Vw + HEAD_ELEMS;            // 8 MiB — aliased with xb (disjoint live ranges)
    bf16_t* xb  = AO;
    bf16_t* wb  = AO + X_N;                   // 6 MiB
    bf16_t* ob  = wb + W_N;                   // 2 MiB
    float*  OAcc = (float*)(ob + O_N);        // 16 MiB fp32
    float*  LAcc = OAcc + (size_t)X_N;        // 256 KiB fp32  (total ~56.25 MiB)

    // 0) zero the attention accumulators
    hipMemsetAsync(OAcc, 0, (size_t)X_N * 4 + (size_t)BATCH * NHEADS * SEQ * 4, stream);
    // 1) fp32 -> bf16 for x, qkv_proj, o_proj
    convert_kernel<<<dim3(4096), 256, 0, stream>>>(x, qkvw, ow, xb, wb, ob);
    // 2) QKV projection + fused RoPE -> head-major bf16 Q/K/V
    qkv_gemm_kernel<<<dim3(24, 32), 256, 0, stream>>>(xb, wb, pos, Qw, Kw, Vw);
    // 3) split-K causal flash attention (128-q blocks) -> fp32 partials
    attn_kernel<<<dim3(40, 32), 256, 0, stream>>>(Qw, Kw, Vw, OAcc, LAcc);
    // 4) normalize -> AO bf16
    norm_kernel<<<dim3(4096), 256, 0, stream>>>(OAcc, LAcc, AO);
    // 5) output projection (128x64 tiles, 512 blocks) -> fp32 d_out
    out_gemm_kernel<<<dim3(16, 32), 256, 0, stream>>>(AO, ob, out);
}